// Round 6
// baseline (1494.165 us; speedup 1.0000x reference)
//
#include <hip/hip_runtime.h>
#include <hip/hip_bf16.h>
#include <math.h>

typedef unsigned short u16;

#define DEVI static __device__ __forceinline__

DEVI float b2f(u16 u) { union { unsigned int i; float f; } v; v.i = ((unsigned int)u) << 16; return v.f; }
DEVI u16 f2b(float f) {
  union { float f; unsigned int i; } v; v.f = f;
  unsigned int x = v.i;
  return (u16)((x + 0x7fffu + ((x >> 16) & 1u)) >> 16);
}

constexpr int T_ = 1024, D_ = 1024, HD_ = 64, KV_ = 512, DH_ = 4096, M_ = 2048;
#define NEGBIG (-1e30f)

#define FMA16(ACC, A, B) \
  ACC[0][0] += A.x*B.x; ACC[0][1] += A.x*B.y; ACC[0][2] += A.x*B.z; ACC[0][3] += A.x*B.w; \
  ACC[1][0] += A.y*B.x; ACC[1][1] += A.y*B.y; ACC[1][2] += A.y*B.z; ACC[1][3] += A.y*B.w; \
  ACC[2][0] += A.z*B.x; ACC[2][1] += A.z*B.y; ACC[2][2] += A.z*B.z; ACC[2][3] += A.z*B.w; \
  ACC[3][0] += A.w*B.x; ACC[3][1] += A.w*B.y; ACC[3][2] += A.w*B.z; ACC[3][3] += A.w*B.w;

// ---------------- RMSNorm (f32 in -> f32 out) ----------------
__global__ __launch_bounds__(256) void k_rms1(const float* __restrict__ x, const float* __restrict__ w,
                                              float* __restrict__ out) {
  int row = blockIdx.x, tid = threadIdx.x;
  float4 v = *(const float4*)&x[(size_t)row * D_ + tid * 4];
  float ss = v.x*v.x + v.y*v.y + v.z*v.z + v.w*v.w;
  #pragma unroll
  for (int m = 32; m >= 1; m >>= 1) ss += __shfl_xor(ss, m, 64);
  __shared__ float red[4];
  if ((tid & 63) == 0) red[tid >> 6] = ss;
  __syncthreads();
  ss = red[0] + red[1] + red[2] + red[3];
  float sc = 1.0f / sqrtf(ss * (1.0f / 1024.0f) + 1e-6f);
  float4 wv = *(const float4*)&w[tid * 4];
  float4 o; o.x = wv.x*v.x*sc; o.y = wv.y*v.y*sc; o.z = wv.z*v.z*sc; o.w = wv.w*v.w*sc;
  *(float4*)&out[(size_t)row * D_ + tid * 4] = o;
}

// ---------------- LayerNorm on latent (in-place, 512 cols) ----------------
__global__ __launch_bounds__(256) void k_ln(float* __restrict__ lat, const float* __restrict__ g,
                                            const float* __restrict__ bb) {
  int row = blockIdx.x, tid = threadIdx.x;
  float* r = lat + (size_t)row * KV_;
  float v0 = r[tid], v1 = r[tid + 256];
  float s = v0 + v1;
  #pragma unroll
  for (int m = 32; m >= 1; m >>= 1) s += __shfl_xor(s, m, 64);
  __shared__ float red[4];
  if ((tid & 63) == 0) red[tid >> 6] = s;
  __syncthreads();
  float mu = (red[0] + red[1] + red[2] + red[3]) * (1.0f / 512.0f);
  __syncthreads();
  float d0 = v0 - mu, d1 = v1 - mu;
  float ss = d0*d0 + d1*d1;
  #pragma unroll
  for (int m = 32; m >= 1; m >>= 1) ss += __shfl_xor(ss, m, 64);
  if ((tid & 63) == 0) red[tid >> 6] = ss;
  __syncthreads();
  float var = (red[0] + red[1] + red[2] + red[3]) * (1.0f / 512.0f);
  float sc = 1.0f / sqrtf(var + 1e-5f);
  r[tid]       = d0 * sc * g[tid]       + bb[tid];
  r[tid + 256] = d1 * sc * g[tid + 256] + bb[tid + 256];
}

// ---------------- fp32 GEMM: C[M,N] = A[M,K] @ Bw[N,K]^T (+ f32 residual) ----------------
__global__ __launch_bounds__(256) void k_gemm32(const float* __restrict__ A, const float* __restrict__ Bw,
                                                float* __restrict__ C, const float* __restrict__ resid,
                                                int N, int K) {
  __shared__ __align__(16) float As[16][68];
  __shared__ __align__(16) float Bs[16][68];
  int nb = blockIdx.x * 64, mb = blockIdx.y * 64;
  int tid = threadIdx.x, tx = tid & 15, ty = tid >> 4;
  int lr = tid >> 2, lk = (tid & 3) * 4;
  float acc[4][4] = {};
  for (int kb = 0; kb < K; kb += 16) {
    __syncthreads();
    float4 av = *(const float4*)&A[(size_t)(mb + lr) * K + kb + lk];
    float4 bv = *(const float4*)&Bw[(size_t)(nb + lr) * K + kb + lk];
    As[lk + 0][lr] = av.x; As[lk + 1][lr] = av.y; As[lk + 2][lr] = av.z; As[lk + 3][lr] = av.w;
    Bs[lk + 0][lr] = bv.x; Bs[lk + 1][lr] = bv.y; Bs[lk + 2][lr] = bv.z; Bs[lk + 3][lr] = bv.w;
    __syncthreads();
    #pragma unroll
    for (int kk = 0; kk < 16; ++kk) {
      float4 a = *(const float4*)&As[kk][ty * 4];
      float4 b = *(const float4*)&Bs[kk][tx * 4];
      FMA16(acc, a, b);
    }
  }
  #pragma unroll
  for (int i = 0; i < 4; ++i) {
    size_t base = (size_t)(mb + ty * 4 + i) * N + nb + tx * 4;
    float4 o; o.x = acc[i][0]; o.y = acc[i][1]; o.z = acc[i][2]; o.w = acc[i][3];
    if (resid) {
      float4 rv = *(const float4*)&resid[base];
      o.x += rv.x; o.y += rv.y; o.z += rv.z; o.w += rv.w;
    }
    *(float4*)&C[base] = o;
  }
}

// ---------------- RoPE (in-place on q and k, f32) ----------------
__global__ __launch_bounds__(256) void k_rope(float* __restrict__ q, float* __restrict__ k) {
  int g = blockIdx.x * 256 + threadIdx.x;
  int j = g & 31;
  int h = (g >> 5) & 15;
  int row = g >> 9;
  int t = row & (T_ - 1);
  float p = (float)pow(10000.0, (double)j * (1.0 / 32.0));
  float invf = 1.0f / p;
  float ang = (float)t * invf;
  float sn, cs; sincosf(ang, &sn, &cs);
  size_t base = (size_t)row * D_ + h * 64 + j;
  float x1 = q[base], x2 = q[base + 32];
  q[base] = x1 * cs - x2 * sn; q[base + 32] = x1 * sn + x2 * cs;
  x1 = k[base]; x2 = k[base + 32];
  k[base] = x1 * cs - x2 * sn; k[base + 32] = x1 * sn + x2 * cs;
}

// ---------------- Attention, two-pass softmax, one wave per q row, in-place out over q ----------------
__global__ __launch_bounds__(256) void k_attn2(float* __restrict__ qio, const float* __restrict__ kk_,
                                               const float* __restrict__ v) {
  int rg = blockIdx.x, h = blockIdx.y, bb = blockIdx.z;
  __shared__ __align__(16) float qs[4][64];
  __shared__ __align__(16) float ks[64][65];
  __shared__ __align__(16) float scb[4][1024];
  int tid = threadIdx.x, wi = tid >> 6, lane = tid & 63;
  size_t rowbase = (size_t)bb * T_;
  int colbase = h * HD_;
  int r0 = rg * 4;
  int qrow = r0 + wi;
  qs[wi][lane] = qio[(rowbase + qrow) * D_ + colbase + lane];
  int nkt = ((r0 + 3) >> 6) + 1;
  int lr = tid >> 2, ld = (tid & 3) * 16;
  for (int kt = 0; kt < nkt; ++kt) {
    __syncthreads();
    const float* kr = kk_ + (rowbase + kt * 64 + lr) * D_ + colbase + ld;
    #pragma unroll
    for (int c = 0; c < 16; c += 4) {
      float4 t4 = *(const float4*)&kr[c];
      ks[lr][ld + c + 0] = t4.x; ks[lr][ld + c + 1] = t4.y;
      ks[lr][ld + c + 2] = t4.z; ks[lr][ld + c + 3] = t4.w;
    }
    __syncthreads();
    int kcol = kt * 64 + lane;
    float s = 0.f;
    #pragma unroll
    for (int d = 0; d < 64; ++d) s += qs[wi][d] * ks[lane][d];
    s *= 0.125f;
    if (kcol > qrow) s = NEGBIG;
    scb[wi][kcol] = s;
  }
  int nc = nkt * 64;
  float mx = NEGBIG;
  for (int c = lane; c < nc; c += 64) mx = fmaxf(mx, scb[wi][c]);
  #pragma unroll
  for (int m = 32; m >= 1; m >>= 1) mx = fmaxf(mx, __shfl_xor(mx, m, 64));
  float l = 0.f;
  for (int c = lane; c < nc; c += 64) {
    float p = expf(scb[wi][c] - mx);
    scb[wi][c] = p;
    l += p;
  }
  #pragma unroll
  for (int m = 32; m >= 1; m >>= 1) l += __shfl_xor(l, m, 64);
  float acc = 0.f;
  for (int kk = 0; kk <= qrow; ++kk)
    acc += scb[wi][kk] * v[(rowbase + kk) * D_ + colbase + lane];
  qio[(rowbase + qrow) * D_ + colbase + lane] = acc / l;
}

// ---------------- MoE gate ----------------
__global__ __launch_bounds__(256) void k_init(int* cnt) { if (threadIdx.x < 4) cnt[threadIdx.x] = 0; }

__global__ __launch_bounds__(256) void k_gate(const float* __restrict__ h2, const float* __restrict__ gw,
                                              const float* __restrict__ gb, int* __restrict__ expert,
                                              int* __restrict__ cnt) {
  int wid = threadIdx.x >> 6, lane = threadIdx.x & 63;
  int t = blockIdx.x * 4 + wid;
  const float* hr = h2 + (size_t)t * D_;
  float a0 = 0, a1 = 0, a2 = 0, a3 = 0;
  for (int c = lane; c < D_; c += 64) {
    float xv = hr[c];
    a0 += xv * gw[c];
    a1 += xv * gw[D_ + c];
    a2 += xv * gw[2 * D_ + c];
    a3 += xv * gw[3 * D_ + c];
  }
  #pragma unroll
  for (int m = 32; m >= 1; m >>= 1) {
    a0 += __shfl_xor(a0, m, 64); a1 += __shfl_xor(a1, m, 64);
    a2 += __shfl_xor(a2, m, 64); a3 += __shfl_xor(a3, m, 64);
  }
  if (lane == 0) {
    float l0 = a0 + gb[0], l1 = a1 + gb[1], l2 = a2 + gb[2], l3 = a3 + gb[3];
    int best = 0; float bv = l0;
    if (l1 > bv) { bv = l1; best = 1; }
    if (l2 > bv) { bv = l2; best = 2; }
    if (l3 > bv) { bv = l3; best = 3; }
    expert[t] = best;
    atomicAdd(&cnt[best], 1);
  }
}

__global__ __launch_bounds__(256) void k_scatter(const int* __restrict__ expert, const int* __restrict__ cnt,
                                                 int* __restrict__ off, int* __restrict__ sorted) {
  __shared__ int cur[4];
  if (threadIdx.x == 0) {
    int o0 = 0, o1 = cnt[0], o2 = o1 + cnt[1], o3 = o2 + cnt[2];
    off[0] = o0; off[1] = o1; off[2] = o2; off[3] = o3;
    cur[0] = o0; cur[1] = o1; cur[2] = o2; cur[3] = o3;
  }
  __syncthreads();
  for (int t = threadIdx.x; t < M_; t += 256) {
    int e = expert[t];
    int p = atomicAdd(&cur[e], 1);
    sorted[p] = t;
  }
}

// ---------------- MoE GEMM 1 (fp32 vector): hbuf = bf16(relu(h2[gather] @ W1[e]^T + b1[e])) ----------------
__global__ __launch_bounds__(256) void k_moe1f(const float* __restrict__ A, const float* __restrict__ W1,
                                               const float* __restrict__ b1, const int* __restrict__ cnt,
                                               const int* __restrict__ off, const int* __restrict__ sorted,
                                               u16* __restrict__ hbuf) {
  int e = blockIdx.z, mt = blockIdx.y, nt = blockIdx.x;
  int rem = cnt[e] - mt * 64;
  if (rem <= 0) return;
  __shared__ __align__(16) float As[16][68];
  __shared__ __align__(16) float Bs[16][68];
  int tid = threadIdx.x, tx = tid & 15, ty = tid >> 4;
  int lr = tid >> 2, lk = (tid & 3) * 4;
  int rr = lr < rem ? lr : rem - 1;
  const float* arow = A + (size_t)sorted[off[e] + mt * 64 + rr] * D_;
  const float* brow = W1 + (size_t)e * DH_ * D_ + (size_t)(nt * 64 + lr) * D_;
  float acc[4][4] = {};
  for (int kb = 0; kb < D_; kb += 16) {
    __syncthreads();
    float4 av = *(const float4*)&arow[kb + lk];
    float4 bv = *(const float4*)&brow[kb + lk];
    As[lk + 0][lr] = av.x; As[lk + 1][lr] = av.y; As[lk + 2][lr] = av.z; As[lk + 3][lr] = av.w;
    Bs[lk + 0][lr] = bv.x; Bs[lk + 1][lr] = bv.y; Bs[lk + 2][lr] = bv.z; Bs[lk + 3][lr] = bv.w;
    __syncthreads();
    #pragma unroll
    for (int kk = 0; kk < 16; ++kk) {
      float4 a = *(const float4*)&As[kk][ty * 4];
      float4 b = *(const float4*)&Bs[kk][tx * 4];
      FMA16(acc, a, b);
    }
  }
  #pragma unroll
  for (int i = 0; i < 4; ++i) {
    int ml = ty * 4 + i;
    if (ml >= rem) continue;
    size_t grow = (size_t)(off[e] + mt * 64 + ml);
    #pragma unroll
    for (int j = 0; j < 4; ++j) {
      int gn = nt * 64 + tx * 4 + j;
      float vv = acc[i][j] + b1[e * DH_ + gn];
      hbuf[grow * DH_ + gn] = f2b(fmaxf(vv, 0.f));
    }
  }
}

// ---------------- MoE GEMM 2 (fp32 vector): out_f32 = x1 + hbuf @ W2[e]^T + b2[e] ----------------
__global__ __launch_bounds__(256) void k_moe2f(const u16* __restrict__ hbuf, const float* __restrict__ W2,
                                               const float* __restrict__ b2w, const float* __restrict__ x1f,
                                               const int* __restrict__ cnt, const int* __restrict__ off,
                                               const int* __restrict__ sorted, float* __restrict__ out) {
  int e = blockIdx.z, mt = blockIdx.y, nt = blockIdx.x;
  int rem = cnt[e] - mt * 64;
  if (rem <= 0) return;
  __shared__ __align__(16) float As[16][68];
  __shared__ __align__(16) float Bs[16][68];
  int tid = threadIdx.x, tx = tid & 15, ty = tid >> 4;
  int lr = tid >> 2, lk = (tid & 3) * 4;
  int rr = lr < rem ? lr : rem - 1;
  const u16* arow = hbuf + (size_t)(off[e] + mt * 64 + rr) * DH_;
  const float* brow = W2 + (size_t)e * D_ * DH_ + (size_t)(nt * 64 + lr) * DH_;
  float acc[4][4] = {};
  for (int kb = 0; kb < DH_; kb += 16) {
    __syncthreads();
    ushort4 av = *(const ushort4*)&arow[kb + lk];
    float4 bv = *(const float4*)&brow[kb + lk];
    As[lk + 0][lr] = b2f(av.x); As[lk + 1][lr] = b2f(av.y);
    As[lk + 2][lr] = b2f(av.z); As[lk + 3][lr] = b2f(av.w);
    Bs[lk + 0][lr] = bv.x; Bs[lk + 1][lr] = bv.y; Bs[lk + 2][lr] = bv.z; Bs[lk + 3][lr] = bv.w;
    __syncthreads();
    #pragma unroll
    for (int kk = 0; kk < 16; ++kk) {
      float4 a = *(const float4*)&As[kk][ty * 4];
      float4 b = *(const float4*)&Bs[kk][tx * 4];
      FMA16(acc, a, b);
    }
  }
  #pragma unroll
  for (int i = 0; i < 4; ++i) {
    int ml = ty * 4 + i;
    if (ml >= rem) continue;
    int tok = sorted[off[e] + mt * 64 + ml];
    #pragma unroll
    for (int j = 0; j < 4; ++j) {
      int gn = nt * 64 + tx * 4 + j;
      out[(size_t)tok * D_ + gn] = acc[i][j] + b2w[e * D_ + gn] + x1f[(size_t)tok * D_ + gn];
    }
  }
}

extern "C" void kernel_launch(void* const* d_in, const int* in_sizes, int n_in,
                              void* d_out, int out_size, void* d_ws, size_t ws_size,
                              hipStream_t stream) {
  // Inputs in setup_inputs() dict order (all fp32). Keep the in_sizes-based
  // order probe as cheap insurance (identity when dict order, per doc).
  int map[16];
  for (int i = 0; i < 16; ++i) map[i] = i;
  if (n_in == 16 && in_sizes[0] == 16777216) {
    const int mm[16] = {15, 13, 14, 4, 2, 5, 6, 3, 12, 11, 10, 9, 0, 7, 1, 8};
    for (int i = 0; i < 16; ++i) map[i] = mm[i];
  } else if (n_in == 16 && in_sizes[0] == 4096) {
    for (int i = 0; i < 16; ++i) map[i] = 15 - i;
  }
  const float* x    = (const float*)d_in[map[0]];
  const float* n1w  = (const float*)d_in[map[1]];
  const float* n2w  = (const float*)d_in[map[2]];
  const float* Wq   = (const float*)d_in[map[3]];
  const float* Wdkv = (const float*)d_in[map[4]];
  const float* Wuk  = (const float*)d_in[map[5]];
  const float* Wuv  = (const float*)d_in[map[6]];
  const float* Wo   = (const float*)d_in[map[7]];
  const float* lng  = (const float*)d_in[map[8]];
  const float* lnb  = (const float*)d_in[map[9]];
  const float* gw   = (const float*)d_in[map[10]];
  const float* gb   = (const float*)d_in[map[11]];
  const float* W1   = (const float*)d_in[map[12]];
  const float* b1   = (const float*)d_in[map[13]];
  const float* W2   = (const float*)d_in[map[14]];
  const float* b2w  = (const float*)d_in[map[15]];
  float* out = (float*)d_out;              // fp32 output per reference dtype
  char* ws = (char*)d_ws;
  const size_t MB = 1ull << 20;
  // Overlay layout, peak 36MB + 20KB. Liveness:
  //  A [0,8)  : h1f (rms1 -> Wq,Wdkv) -> kf (Wuk -> rope -> attn) -> hbuf.lo (moe1 -> moe2)
  //  B [8,16) : qf (Wq -> rope -> attn in-place -> Wo gemm)       -> hbuf.hi
  //  C [16,24): vf (Wuv -> attn)                                  -> h2f (rms2 -> gate,moe1)
  //  D [24,32): x1f (Wo out + resid x; residual for moe2, live to end)
  //  E [32,36): latf (Wdkv -> ln -> Wuk,Wuv)
  //  [36,..)  : ints (cnt/off/expert/sorted ~16.5KB)
  float* h1f  = (float*)(ws + 0);
  float* kf   = (float*)(ws + 0);
  u16*   hbuf = (u16*)(ws + 0);            // 16MB: [0,16)
  float* qf   = (float*)(ws + 8 * MB);
  float* vf   = (float*)(ws + 16 * MB);
  float* h2f  = (float*)(ws + 16 * MB);
  float* x1f  = (float*)(ws + 24 * MB);
  float* latf = (float*)(ws + 32 * MB);
  int*   cnt    = (int*)(ws + 36 * MB);
  int*   off    = cnt + 8;
  int*   expert = cnt + 16;
  int*   sorted = expert + 2048;

  k_rms1<<<2048, 256, 0, stream>>>(x, n1w, h1f);
  k_gemm32<<<dim3(16, 32), 256, 0, stream>>>(h1f, Wq, qf, nullptr, 1024, 1024);
  k_gemm32<<<dim3(8, 32), 256, 0, stream>>>(h1f, Wdkv, latf, nullptr, 512, 1024);
  k_ln<<<2048, 256, 0, stream>>>(latf, lng, lnb);
  k_gemm32<<<dim3(16, 32), 256, 0, stream>>>(latf, Wuk, kf, nullptr, 1024, 512);
  k_gemm32<<<dim3(16, 32), 256, 0, stream>>>(latf, Wuv, vf, nullptr, 1024, 512);
  k_rope<<<4096, 256, 0, stream>>>(qf, kf);
  k_attn2<<<dim3(256, 16, 2), 256, 0, stream>>>(qf, kf, vf);
  k_gemm32<<<dim3(16, 32), 256, 0, stream>>>(qf, Wo, x1f, x, 1024, 1024);
  k_rms1<<<2048, 256, 0, stream>>>(x1f, n2w, h2f);
  k_init<<<1, 64, 0, stream>>>(cnt);
  k_gate<<<512, 256, 0, stream>>>(h2f, gw, gb, expert, cnt);
  k_scatter<<<1, 256, 0, stream>>>(expert, cnt, off, sorted);
  k_moe1f<<<dim3(64, 32, 4), 256, 0, stream>>>(h2f, W1, b1, cnt, off, sorted, hbuf);
  k_moe2f<<<dim3(16, 32, 4), 256, 0, stream>>>(hbuf, W2, b2w, x1f, cnt, off, sorted, out);
}

// Round 7
// 1025.347 us; speedup vs baseline: 1.4572x; 1.4572x over previous
//
#include <hip/hip_runtime.h>
#include <hip/hip_bf16.h>
#include <math.h>

typedef unsigned short u16;
typedef __attribute__((ext_vector_type(4))) float floatx4;
typedef __attribute__((ext_vector_type(8))) short shortx8;

#define DEVI static __device__ __forceinline__

DEVI float b2f(u16 u) { union { unsigned int i; float f; } v; v.i = ((unsigned int)u) << 16; return v.f; }
DEVI u16 f2b(float f) {
  union { float f; unsigned int i; } v; v.f = f;
  unsigned int x = v.i;
  return (u16)((x + 0x7fffu + ((x >> 16) & 1u)) >> 16);
}

constexpr int T_ = 1024, D_ = 1024, HD_ = 64, KV_ = 512, DH_ = 4096, M_ = 2048;
#define NEGBIG (-1e30f)

#define FMA16(ACC, A, B) \
  ACC[0][0] += A.x*B.x; ACC[0][1] += A.x*B.y; ACC[0][2] += A.x*B.z; ACC[0][3] += A.x*B.w; \
  ACC[1][0] += A.y*B.x; ACC[1][1] += A.y*B.y; ACC[1][2] += A.y*B.z; ACC[1][3] += A.y*B.w; \
  ACC[2][0] += A.z*B.x; ACC[2][1] += A.z*B.y; ACC[2][2] += A.z*B.z; ACC[2][3] += A.z*B.w; \
  ACC[3][0] += A.w*B.x; ACC[3][1] += A.w*B.y; ACC[3][2] += A.w*B.z; ACC[3][3] += A.w*B.w;

// ---------------- RMSNorm (f32 in -> f32 out) ----------------
__global__ __launch_bounds__(256) void k_rms1(const float* __restrict__ x, const float* __restrict__ w,
                                              float* __restrict__ out) {
  int row = blockIdx.x, tid = threadIdx.x;
  float4 v = *(const float4*)&x[(size_t)row * D_ + tid * 4];
  float ss = v.x*v.x + v.y*v.y + v.z*v.z + v.w*v.w;
  #pragma unroll
  for (int m = 32; m >= 1; m >>= 1) ss += __shfl_xor(ss, m, 64);
  __shared__ float red[4];
  if ((tid & 63) == 0) red[tid >> 6] = ss;
  __syncthreads();
  ss = red[0] + red[1] + red[2] + red[3];
  float sc = 1.0f / sqrtf(ss * (1.0f / 1024.0f) + 1e-6f);
  float4 wv = *(const float4*)&w[tid * 4];
  float4 o; o.x = wv.x*v.x*sc; o.y = wv.y*v.y*sc; o.z = wv.z*v.z*sc; o.w = wv.w*v.w*sc;
  *(float4*)&out[(size_t)row * D_ + tid * 4] = o;
}

// ---------------- RMSNorm (f32 in -> f32 out + bf16 out) ----------------
__global__ __launch_bounds__(256) void k_rms2b(const float* __restrict__ x, const float* __restrict__ w,
                                               float* __restrict__ outf, u16* __restrict__ outb) {
  int row = blockIdx.x, tid = threadIdx.x;
  float4 v = *(const float4*)&x[(size_t)row * D_ + tid * 4];
  float ss = v.x*v.x + v.y*v.y + v.z*v.z + v.w*v.w;
  #pragma unroll
  for (int m = 32; m >= 1; m >>= 1) ss += __shfl_xor(ss, m, 64);
  __shared__ float red[4];
  if ((tid & 63) == 0) red[tid >> 6] = ss;
  __syncthreads();
  ss = red[0] + red[1] + red[2] + red[3];
  float sc = 1.0f / sqrtf(ss * (1.0f / 1024.0f) + 1e-6f);
  float4 wv = *(const float4*)&w[tid * 4];
  float4 o; o.x = wv.x*v.x*sc; o.y = wv.y*v.y*sc; o.z = wv.z*v.z*sc; o.w = wv.w*v.w*sc;
  *(float4*)&outf[(size_t)row * D_ + tid * 4] = o;
  ushort4 ob; ob.x = f2b(o.x); ob.y = f2b(o.y); ob.z = f2b(o.z); ob.w = f2b(o.w);
  *(ushort4*)&outb[(size_t)row * D_ + tid * 4] = ob;
}

// ---------------- LayerNorm on latent (in-place, 512 cols) ----------------
__global__ __launch_bounds__(256) void k_ln(float* __restrict__ lat, const float* __restrict__ g,
                                            const float* __restrict__ bb) {
  int row = blockIdx.x, tid = threadIdx.x;
  float* r = lat + (size_t)row * KV_;
  float v0 = r[tid], v1 = r[tid + 256];
  float s = v0 + v1;
  #pragma unroll
  for (int m = 32; m >= 1; m >>= 1) s += __shfl_xor(s, m, 64);
  __shared__ float red[4];
  if ((tid & 63) == 0) red[tid >> 6] = s;
  __syncthreads();
  float mu = (red[0] + red[1] + red[2] + red[3]) * (1.0f / 512.0f);
  __syncthreads();
  float d0 = v0 - mu, d1 = v1 - mu;
  float ss = d0*d0 + d1*d1;
  #pragma unroll
  for (int m = 32; m >= 1; m >>= 1) ss += __shfl_xor(ss, m, 64);
  if ((tid & 63) == 0) red[tid >> 6] = ss;
  __syncthreads();
  float var = (red[0] + red[1] + red[2] + red[3]) * (1.0f / 512.0f);
  float sc = 1.0f / sqrtf(var + 1e-5f);
  r[tid]       = d0 * sc * g[tid]       + bb[tid];
  r[tid + 256] = d1 * sc * g[tid + 256] + bb[tid + 256];
}

// ---------------- fp32 GEMM: C[M,N] = A[M,K] @ Bw[N,K]^T (+ f32 residual) ----------------
__global__ __launch_bounds__(256) void k_gemm32(const float* __restrict__ A, const float* __restrict__ Bw,
                                                float* __restrict__ C, const float* __restrict__ resid,
                                                int N, int K) {
  __shared__ __align__(16) float As[16][68];
  __shared__ __align__(16) float Bs[16][68];
  int nb = blockIdx.x * 64, mb = blockIdx.y * 64;
  int tid = threadIdx.x, tx = tid & 15, ty = tid >> 4;
  int lr = tid >> 2, lk = (tid & 3) * 4;
  float acc[4][4] = {};
  for (int kb = 0; kb < K; kb += 16) {
    __syncthreads();
    float4 av = *(const float4*)&A[(size_t)(mb + lr) * K + kb + lk];
    float4 bv = *(const float4*)&Bw[(size_t)(nb + lr) * K + kb + lk];
    As[lk + 0][lr] = av.x; As[lk + 1][lr] = av.y; As[lk + 2][lr] = av.z; As[lk + 3][lr] = av.w;
    Bs[lk + 0][lr] = bv.x; Bs[lk + 1][lr] = bv.y; Bs[lk + 2][lr] = bv.z; Bs[lk + 3][lr] = bv.w;
    __syncthreads();
    #pragma unroll
    for (int kk = 0; kk < 16; ++kk) {
      float4 a = *(const float4*)&As[kk][ty * 4];
      float4 b = *(const float4*)&Bs[kk][tx * 4];
      FMA16(acc, a, b);
    }
  }
  #pragma unroll
  for (int i = 0; i < 4; ++i) {
    size_t base = (size_t)(mb + ty * 4 + i) * N + nb + tx * 4;
    float4 o; o.x = acc[i][0]; o.y = acc[i][1]; o.z = acc[i][2]; o.w = acc[i][3];
    if (resid) {
      float4 rv = *(const float4*)&resid[base];
      o.x += rv.x; o.y += rv.y; o.z += rv.z; o.w += rv.w;
    }
    *(float4*)&C[base] = o;
  }
}

// ---------------- RoPE (in-place on q and k, f32) ----------------
__global__ __launch_bounds__(256) void k_rope(float* __restrict__ q, float* __restrict__ k) {
  int g = blockIdx.x * 256 + threadIdx.x;
  int j = g & 31;
  int h = (g >> 5) & 15;
  int row = g >> 9;
  int t = row & (T_ - 1);
  float p = (float)pow(10000.0, (double)j * (1.0 / 32.0));
  float invf = 1.0f / p;
  float ang = (float)t * invf;
  float sn, cs; sincosf(ang, &sn, &cs);
  size_t base = (size_t)row * D_ + h * 64 + j;
  float x1 = q[base], x2 = q[base + 32];
  q[base] = x1 * cs - x2 * sn; q[base + 32] = x1 * sn + x2 * cs;
  x1 = k[base]; x2 = k[base + 32];
  k[base] = x1 * cs - x2 * sn; k[base + 32] = x1 * sn + x2 * cs;
}

// ---------------- Attention, two-pass softmax, one wave per q row, in-place out over q ----------------
__global__ __launch_bounds__(256) void k_attn2(float* __restrict__ qio, const float* __restrict__ kk_,
                                               const float* __restrict__ v) {
  int rg = blockIdx.x, h = blockIdx.y, bb = blockIdx.z;
  __shared__ __align__(16) float qs[4][64];
  __shared__ __align__(16) float ks[64][65];
  __shared__ __align__(16) float scb[4][1024];
  int tid = threadIdx.x, wi = tid >> 6, lane = tid & 63;
  size_t rowbase = (size_t)bb * T_;
  int colbase = h * HD_;
  int r0 = rg * 4;
  int qrow = r0 + wi;
  qs[wi][lane] = qio[(rowbase + qrow) * D_ + colbase + lane];
  int nkt = ((r0 + 3) >> 6) + 1;
  int lr = tid >> 2, ld = (tid & 3) * 16;
  for (int kt = 0; kt < nkt; ++kt) {
    __syncthreads();
    const float* kr = kk_ + (rowbase + kt * 64 + lr) * D_ + colbase + ld;
    #pragma unroll
    for (int c = 0; c < 16; c += 4) {
      float4 t4 = *(const float4*)&kr[c];
      ks[lr][ld + c + 0] = t4.x; ks[lr][ld + c + 1] = t4.y;
      ks[lr][ld + c + 2] = t4.z; ks[lr][ld + c + 3] = t4.w;
    }
    __syncthreads();
    int kcol = kt * 64 + lane;
    float s = 0.f;
    #pragma unroll
    for (int d = 0; d < 64; ++d) s += qs[wi][d] * ks[lane][d];
    s *= 0.125f;
    if (kcol > qrow) s = NEGBIG;
    scb[wi][kcol] = s;
  }
  int nc = nkt * 64;
  float mx = NEGBIG;
  for (int c = lane; c < nc; c += 64) mx = fmaxf(mx, scb[wi][c]);
  #pragma unroll
  for (int m = 32; m >= 1; m >>= 1) mx = fmaxf(mx, __shfl_xor(mx, m, 64));
  float l = 0.f;
  for (int c = lane; c < nc; c += 64) {
    float p = expf(scb[wi][c] - mx);
    scb[wi][c] = p;
    l += p;
  }
  #pragma unroll
  for (int m = 32; m >= 1; m >>= 1) l += __shfl_xor(l, m, 64);
  float acc = 0.f;
  for (int kk = 0; kk <= qrow; ++kk)
    acc += scb[wi][kk] * v[(rowbase + kk) * D_ + colbase + lane];
  qio[(rowbase + qrow) * D_ + colbase + lane] = acc / l;
}

// ---------------- MoE gate ----------------
__global__ __launch_bounds__(256) void k_init(int* cnt) { if (threadIdx.x < 4) cnt[threadIdx.x] = 0; }

__global__ __launch_bounds__(256) void k_gate(const float* __restrict__ h2, const float* __restrict__ gw,
                                              const float* __restrict__ gb, int* __restrict__ expert,
                                              int* __restrict__ cnt) {
  int wid = threadIdx.x >> 6, lane = threadIdx.x & 63;
  int t = blockIdx.x * 4 + wid;
  const float* hr = h2 + (size_t)t * D_;
  float a0 = 0, a1 = 0, a2 = 0, a3 = 0;
  for (int c = lane; c < D_; c += 64) {
    float xv = hr[c];
    a0 += xv * gw[c];
    a1 += xv * gw[D_ + c];
    a2 += xv * gw[2 * D_ + c];
    a3 += xv * gw[3 * D_ + c];
  }
  #pragma unroll
  for (int m = 32; m >= 1; m >>= 1) {
    a0 += __shfl_xor(a0, m, 64); a1 += __shfl_xor(a1, m, 64);
    a2 += __shfl_xor(a2, m, 64); a3 += __shfl_xor(a3, m, 64);
  }
  if (lane == 0) {
    float l0 = a0 + gb[0], l1 = a1 + gb[1], l2 = a2 + gb[2], l3 = a3 + gb[3];
    int best = 0; float bv = l0;
    if (l1 > bv) { bv = l1; best = 1; }
    if (l2 > bv) { bv = l2; best = 2; }
    if (l3 > bv) { bv = l3; best = 3; }
    expert[t] = best;
    atomicAdd(&cnt[best], 1);
  }
}

__global__ __launch_bounds__(256) void k_scatter(const int* __restrict__ expert, const int* __restrict__ cnt,
                                                 int* __restrict__ off, int* __restrict__ sorted) {
  __shared__ int cur[4];
  if (threadIdx.x == 0) {
    int o0 = 0, o1 = cnt[0], o2 = o1 + cnt[1], o3 = o2 + cnt[2];
    off[0] = o0; off[1] = o1; off[2] = o2; off[3] = o3;
    cur[0] = o0; cur[1] = o1; cur[2] = o2; cur[3] = o3;
  }
  __syncthreads();
  for (int t = threadIdx.x; t < M_; t += 256) {
    int e = expert[t];
    int p = atomicAdd(&cur[e], 1);
    sorted[p] = t;
  }
}

// ---------------- MoE MFMA GEMM 1: hbuf = bf16(relu(h2b[gather] @ W1[e]^T + b1[e])) ----------------
// 64x64 tile, 4 waves in 2x2 quadrants of 32x32, mfma_f32_16x16x32_bf16.
__global__ __launch_bounds__(256) void k_moe1(const u16* __restrict__ A, const float* __restrict__ W1,
                                              const float* __restrict__ b1, const int* __restrict__ cnt,
                                              const int* __restrict__ off, const int* __restrict__ sorted,
                                              u16* __restrict__ hbuf) {
  int e = blockIdx.z, mt = blockIdx.y, nt = blockIdx.x;
  int rem = cnt[e] - mt * 64;
  if (rem <= 0) return;
  __shared__ __align__(16) u16 As[64][72];
  __shared__ __align__(16) u16 Bs[64][72];
  int tid = threadIdx.x, lane = tid & 63, wave = tid >> 6;
  int wm = (wave >> 1) * 32, wn = (wave & 1) * 32;
  int lr = tid >> 2, lc = (tid & 3) * 16;
  int rr = lr < rem ? lr : rem - 1;
  const u16* arow = A + (size_t)sorted[off[e] + mt * 64 + rr] * D_;
  const float* brow = W1 + (size_t)e * DH_ * D_ + (size_t)(nt * 64 + lr) * D_;
  floatx4 z = {0.f, 0.f, 0.f, 0.f};
  floatx4 acc00 = z, acc01 = z, acc10 = z, acc11 = z;
  int fm = lane & 15, fkq = (lane >> 4) * 8;
  for (int kb = 0; kb < D_; kb += 64) {
    __syncthreads();
    *(uint4*)&As[lr][lc]     = *(const uint4*)&arow[kb + lc];
    *(uint4*)&As[lr][lc + 8] = *(const uint4*)&arow[kb + lc + 8];
    #pragma unroll
    for (int c = 0; c < 16; c += 4) {
      float4 f = *(const float4*)&brow[kb + lc + c];
      ushort4 u; u.x = f2b(f.x); u.y = f2b(f.y); u.z = f2b(f.z); u.w = f2b(f.w);
      *(ushort4*)&Bs[lr][lc + c] = u;
    }
    __syncthreads();
    #pragma unroll
    for (int ks = 0; ks < 64; ks += 32) {
      shortx8 a0  = *(const shortx8*)&As[wm + fm][ks + fkq];
      shortx8 a1  = *(const shortx8*)&As[wm + 16 + fm][ks + fkq];
      shortx8 b0  = *(const shortx8*)&Bs[wn + fm][ks + fkq];
      shortx8 b1v = *(const shortx8*)&Bs[wn + 16 + fm][ks + fkq];
      acc00 = __builtin_amdgcn_mfma_f32_16x16x32_bf16(a0, b0,  acc00, 0, 0, 0);
      acc01 = __builtin_amdgcn_mfma_f32_16x16x32_bf16(a0, b1v, acc01, 0, 0, 0);
      acc10 = __builtin_amdgcn_mfma_f32_16x16x32_bf16(a1, b0,  acc10, 0, 0, 0);
      acc11 = __builtin_amdgcn_mfma_f32_16x16x32_bf16(a1, b1v, acc11, 0, 0, 0);
    }
  }
  int q4 = (lane >> 4) * 4, cix = lane & 15;
  #pragma unroll
  for (int im = 0; im < 2; ++im) {
    #pragma unroll
    for (int rg = 0; rg < 4; ++rg) {
      int ml = wm + im * 16 + q4 + rg;
      if (ml >= rem) continue;
      size_t grow = (size_t)(off[e] + mt * 64 + ml);
      #pragma unroll
      for (int in = 0; in < 2; ++in) {
        int gn = nt * 64 + wn + in * 16 + cix;
        float vv = (im == 0 ? (in == 0 ? acc00[rg] : acc01[rg]) : (in == 0 ? acc10[rg] : acc11[rg]));
        vv += b1[e * DH_ + gn];
        hbuf[grow * DH_ + gn] = f2b(fmaxf(vv, 0.f));
      }
    }
  }
}

// ---------------- MoE MFMA GEMM 2: out_f32 = x1 + hbuf @ W2[e]^T + b2[e] ----------------
__global__ __launch_bounds__(256) void k_moe2(const u16* __restrict__ hbuf, const float* __restrict__ W2,
                                              const float* __restrict__ b2w, const float* __restrict__ x1f,
                                              const int* __restrict__ cnt, const int* __restrict__ off,
                                              const int* __restrict__ sorted, float* __restrict__ out) {
  int e = blockIdx.z, mt = blockIdx.y, nt = blockIdx.x;
  int rem = cnt[e] - mt * 64;
  if (rem <= 0) return;
  __shared__ __align__(16) u16 As[64][72];
  __shared__ __align__(16) u16 Bs[64][72];
  int tid = threadIdx.x, lane = tid & 63, wave = tid >> 6;
  int wm = (wave >> 1) * 32, wn = (wave & 1) * 32;
  int lr = tid >> 2, lc = (tid & 3) * 16;
  int rr = lr < rem ? lr : rem - 1;
  const u16* arow = hbuf + (size_t)(off[e] + mt * 64 + rr) * DH_;
  const float* brow = W2 + (size_t)e * D_ * DH_ + (size_t)(nt * 64 + lr) * DH_;
  floatx4 z = {0.f, 0.f, 0.f, 0.f};
  floatx4 acc00 = z, acc01 = z, acc10 = z, acc11 = z;
  int fm = lane & 15, fkq = (lane >> 4) * 8;
  for (int kb = 0; kb < DH_; kb += 64) {
    __syncthreads();
    *(uint4*)&As[lr][lc]     = *(const uint4*)&arow[kb + lc];
    *(uint4*)&As[lr][lc + 8] = *(const uint4*)&arow[kb + lc + 8];
    #pragma unroll
    for (int c = 0; c < 16; c += 4) {
      float4 f = *(const float4*)&brow[kb + lc + c];
      ushort4 u; u.x = f2b(f.x); u.y = f2b(f.y); u.z = f2b(f.z); u.w = f2b(f.w);
      *(ushort4*)&Bs[lr][lc + c] = u;
    }
    __syncthreads();
    #pragma unroll
    for (int ks = 0; ks < 64; ks += 32) {
      shortx8 a0  = *(const shortx8*)&As[wm + fm][ks + fkq];
      shortx8 a1  = *(const shortx8*)&As[wm + 16 + fm][ks + fkq];
      shortx8 b0  = *(const shortx8*)&Bs[wn + fm][ks + fkq];
      shortx8 b1v = *(const shortx8*)&Bs[wn + 16 + fm][ks + fkq];
      acc00 = __builtin_amdgcn_mfma_f32_16x16x32_bf16(a0, b0,  acc00, 0, 0, 0);
      acc01 = __builtin_amdgcn_mfma_f32_16x16x32_bf16(a0, b1v, acc01, 0, 0, 0);
      acc10 = __builtin_amdgcn_mfma_f32_16x16x32_bf16(a1, b0,  acc10, 0, 0, 0);
      acc11 = __builtin_amdgcn_mfma_f32_16x16x32_bf16(a1, b1v, acc11, 0, 0, 0);
    }
  }
  int q4 = (lane >> 4) * 4, cix = lane & 15;
  #pragma unroll
  for (int im = 0; im < 2; ++im) {
    #pragma unroll
    for (int rg = 0; rg < 4; ++rg) {
      int ml = wm + im * 16 + q4 + rg;
      if (ml >= rem) continue;
      int tok = sorted[off[e] + mt * 64 + ml];
      #pragma unroll
      for (int in = 0; in < 2; ++in) {
        int gn = nt * 64 + wn + in * 16 + cix;
        float vv = (im == 0 ? (in == 0 ? acc00[rg] : acc01[rg]) : (in == 0 ? acc10[rg] : acc11[rg]));
        out[(size_t)tok * D_ + gn] = vv + b2w[e * D_ + gn] + x1f[(size_t)tok * D_ + gn];
      }
    }
  }
}

extern "C" void kernel_launch(void* const* d_in, const int* in_sizes, int n_in,
                              void* d_out, int out_size, void* d_ws, size_t ws_size,
                              hipStream_t stream) {
  int map[16];
  for (int i = 0; i < 16; ++i) map[i] = i;
  if (n_in == 16 && in_sizes[0] == 16777216) {
    const int mm[16] = {15, 13, 14, 4, 2, 5, 6, 3, 12, 11, 10, 9, 0, 7, 1, 8};
    for (int i = 0; i < 16; ++i) map[i] = mm[i];
  } else if (n_in == 16 && in_sizes[0] == 4096) {
    for (int i = 0; i < 16; ++i) map[i] = 15 - i;
  }
  const float* x    = (const float*)d_in[map[0]];
  const float* n1w  = (const float*)d_in[map[1]];
  const float* n2w  = (const float*)d_in[map[2]];
  const float* Wq   = (const float*)d_in[map[3]];
  const float* Wdkv = (const float*)d_in[map[4]];
  const float* Wuk  = (const float*)d_in[map[5]];
  const float* Wuv  = (const float*)d_in[map[6]];
  const float* Wo   = (const float*)d_in[map[7]];
  const float* lng  = (const float*)d_in[map[8]];
  const float* lnb  = (const float*)d_in[map[9]];
  const float* gw   = (const float*)d_in[map[10]];
  const float* gb   = (const float*)d_in[map[11]];
  const float* W1   = (const float*)d_in[map[12]];
  const float* b1   = (const float*)d_in[map[13]];
  const float* W2   = (const float*)d_in[map[14]];
  const float* b2w  = (const float*)d_in[map[15]];
  float* out = (float*)d_out;
  char* ws = (char*)d_ws;
  const size_t MB = 1ull << 20;
  // Overlay layout, peak 36MB + 20KB (same as round 6 + h2b over dead latf):
  //  A [0,8)  : h1f (rms1 -> Wq,Wdkv) -> kf (Wuk -> rope -> attn) -> hbuf.lo (moe1 -> moe2)
  //  B [8,16) : qf (Wq -> rope -> attn in-place -> Wo gemm)       -> hbuf.hi
  //  C [16,24): vf (Wuv -> attn)                                  -> h2f (rms2 -> gate)
  //  D [24,32): x1f (Wo out + resid x; residual for moe2, live to end)
  //  E [32,36): latf (Wdkv -> ln -> Wuk,Wuv)                      -> h2b bf16 (rms2 -> moe1)
  float* h1f  = (float*)(ws + 0);
  float* kf   = (float*)(ws + 0);
  u16*   hbuf = (u16*)(ws + 0);            // 16MB: [0,16)
  float* qf   = (float*)(ws + 8 * MB);
  float* vf   = (float*)(ws + 16 * MB);
  float* h2f  = (float*)(ws + 16 * MB);
  float* x1f  = (float*)(ws + 24 * MB);
  float* latf = (float*)(ws + 32 * MB);
  u16*   h2b  = (u16*)(ws + 32 * MB);
  int*   cnt    = (int*)(ws + 36 * MB);
  int*   off    = cnt + 8;
  int*   expert = cnt + 16;
  int*   sorted = expert + 2048;

  k_rms1<<<2048, 256, 0, stream>>>(x, n1w, h1f);
  k_gemm32<<<dim3(16, 32), 256, 0, stream>>>(h1f, Wq, qf, nullptr, 1024, 1024);
  k_gemm32<<<dim3(8, 32), 256, 0, stream>>>(h1f, Wdkv, latf, nullptr, 512, 1024);
  k_ln<<<2048, 256, 0, stream>>>(latf, lng, lnb);
  k_gemm32<<<dim3(16, 32), 256, 0, stream>>>(latf, Wuk, kf, nullptr, 1024, 512);
  k_gemm32<<<dim3(16, 32), 256, 0, stream>>>(latf, Wuv, vf, nullptr, 1024, 512);
  k_rope<<<4096, 256, 0, stream>>>(qf, kf);
  k_attn2<<<dim3(256, 16, 2), 256, 0, stream>>>(qf, kf, vf);
  k_gemm32<<<dim3(16, 32), 256, 0, stream>>>(qf, Wo, x1f, x, 1024, 1024);
  k_rms2b<<<2048, 256, 0, stream>>>(x1f, n2w, h2f, h2b);
  k_init<<<1, 64, 0, stream>>>(cnt);
  k_gate<<<512, 256, 0, stream>>>(h2f, gw, gb, expert, cnt);
  k_scatter<<<1, 256, 0, stream>>>(expert, cnt, off, sorted);
  k_moe1<<<dim3(64, 32, 4), 256, 0, stream>>>(h2b, W1, b1, cnt, off, sorted, hbuf);
  k_moe2<<<dim3(16, 32, 4), 256, 0, stream>>>(hbuf, W2, b2w, x1f, cnt, off, sorted, out);
}